// Round 11
// baseline (264.885 us; speedup 1.0000x reference)
//
#include <hip/hip_runtime.h>

#define N_NODES  50000
#define N_EDGESC 1600000
#define N_GRAPHS 64
#define NBUCK    196      // ceil(50000/256) buckets of 256 dst nodes
#define CHUNK    2048     // edges per hist/scatter block
#define NBLK     782      // ceil(E/CHUNK)

static __device__ __forceinline__ unsigned short f2bf(float f) {
  unsigned u = __float_as_uint(f);
  u += 0x7FFF + ((u >> 16) & 1);          // RNE
  return (unsigned short)(u >> 16);
}
static __device__ __forceinline__ float bfLo(unsigned u) {
  return __uint_as_float(u << 16);
}
static __device__ __forceinline__ float bfHi(unsigned u) {
  return __uint_as_float(u & 0xFFFF0000u);
}

static __device__ __forceinline__ int lowerb(const int* a, int n, int v) {
  int lo = 0, hi = n;
  while (lo < hi) { int m = (lo + hi) >> 1; if (a[m] < v) lo = m + 1; else hi = m; }
  return lo;
}

// Pass 1: per-block bucket histogram (LDS only) -> bcnt[bucket][blk].
// Block 0 also zeros gsum.
__global__ __launch_bounds__(256) void k_hist(const int* __restrict__ dst,
                                              int* __restrict__ bcnt,
                                              float* __restrict__ gsum, int E) {
  __shared__ int hist[NBUCK];
  int t = threadIdx.x, blk = blockIdx.x;
  if (t < NBUCK) hist[t] = 0;
  if (blk == 0) {
    for (int i = t; i < N_GRAPHS * 64; i += 256) gsum[i] = 0.f;
  }
  __syncthreads();
  int e0 = blk * CHUNK;
#pragma unroll
  for (int i = 0; i < CHUNK; i += 256) {
    int e = e0 + i + t;
    if (e < E) atomicAdd(&hist[dst[e] >> 8], 1);
  }
  __syncthreads();
  if (t < NBUCK) bcnt[(size_t)t * NBLK + blk] = hist[t];
}

// Pass 2: per-bucket exclusive scan across blocks (in place) + bucket totals.
__global__ __launch_bounds__(256) void k_cscan(int* __restrict__ bcnt,
                                               int* __restrict__ btot) {
  __shared__ int sm[256];
  int b = blockIdx.x, t = threadIdx.x;
  int* p = bcnt + (size_t)b * NBLK;
  int carry = 0;
  for (int tile = 0; tile < (NBLK + 255) / 256; ++tile) {
    int idx = tile * 256 + t;
    int v = (idx < NBLK) ? p[idx] : 0;
    sm[t] = v;
    __syncthreads();
    for (int o = 1; o < 256; o <<= 1) {
      int add = (t >= o) ? sm[t - o] : 0;
      __syncthreads();
      sm[t] += add;
      __syncthreads();
    }
    int incl = sm[t];
    int total = sm[255];
    if (idx < NBLK) p[idx] = incl - v + carry;
    carry += total;
    __syncthreads();
  }
  if (t == 0) btot[b] = carry;
}

// Pass 3: scatter edges to final bucket-contiguous positions.
__global__ __launch_bounds__(256) void k_scatter(const int* __restrict__ src,
                                                 const int* __restrict__ dst,
                                                 const int* __restrict__ bcnt,
                                                 const int* __restrict__ btot,
                                                 unsigned* __restrict__ bbuf, int E) {
  __shared__ int base[NBUCK], cur[NBUCK], sm[256];
  int t = threadIdx.x, blk = blockIdx.x;
  int v = (t < NBUCK) ? btot[t] : 0;
  sm[t] = v;
  __syncthreads();
  for (int o = 1; o < 256; o <<= 1) {
    int add = (t >= o) ? sm[t - o] : 0;
    __syncthreads();
    sm[t] += add;
    __syncthreads();
  }
  if (t < NBUCK) {
    base[t] = (sm[t] - v) + bcnt[(size_t)t * NBLK + blk];
    cur[t] = 0;
  }
  __syncthreads();
  int e0 = blk * CHUNK;
#pragma unroll
  for (int i = 0; i < CHUNK; i += 256) {
    int e = e0 + i + t;
    if (e < E) {
      int d = dst[e], b = d >> 8;
      int pos = base[b] + atomicAdd(&cur[b], 1);
      bbuf[pos] = ((unsigned)(d & 255) << 24) | (unsigned)src[e];
    }
  }
}

// Pass 4: per-bucket counting sort -> csr + row_off + dinv. 512 threads.
__global__ __launch_bounds__(512) void k_bsort(const unsigned* __restrict__ bbuf,
                                               const int* __restrict__ btot,
                                               int* __restrict__ csr,
                                               int* __restrict__ row_off,
                                               float* __restrict__ dinv) {
  __shared__ int hist[256], off[256], cur[256], sm[256];
  int b = blockIdx.x, t = threadIdx.x;
  if (t < 256) {
    int v = (t < NBUCK) ? btot[t] : 0;
    sm[t] = v;
    hist[t] = 0; cur[t] = 0;
  }
  __syncthreads();
  for (int o = 1; o < 256; o <<= 1) {
    int add = 0;
    if (t < 256 && t >= o) add = sm[t - o];
    __syncthreads();
    if (t < 256) sm[t] += add;
    __syncthreads();
  }
  int gb = (b > 0) ? sm[b - 1] : 0;
  int cnt = btot[b];
  const unsigned* bp = bbuf + gb;
  for (int i = t; i < cnt; i += 512) atomicAdd(&hist[bp[i] >> 24], 1);
  __syncthreads();
  if (t < 256) off[t] = hist[t];
  __syncthreads();
  for (int o = 1; o < 256; o <<= 1) {
    int add = 0;
    if (t < 256 && t >= o) add = off[t - o];
    __syncthreads();
    if (t < 256) off[t] += add;
    __syncthreads();
  }
  if (t < 256) {
    int excl = off[t] - hist[t];
    off[t] = excl;
    int idx = (b << 8) + t;
    if (idx <= N_NODES) row_off[idx] = gb + excl;
    if (idx < N_NODES)  dinv[idx] = rsqrtf((float)(hist[t] + 1));  // +1 self-loop
  }
  __syncthreads();
  for (int i = t; i < cnt; i += 512) {
    unsigned v = bp[i];
    int ld = v >> 24;
    int pos = atomicAdd(&cur[ld], 1);
    csr[gb + off[ld] + pos] = (int)(v & 0xFFFFFFu);
  }
}

// out_bf16[i][c] = bf16( (x[i,:] @ W[:,c]) * dinv[i] )
template <int K>
__global__ __launch_bounds__(256) void k_gemm(const float* __restrict__ x,
                                              const float* __restrict__ W,
                                              const float* __restrict__ dinv,
                                              unsigned short* __restrict__ out, int N) {
  constexpr int KS = 64;            // K-step
  constexpr int KP = KS + 4;        // padded xs row stride
  __shared__ float xs[64 * KP];     // 17.4 KB
  __shared__ float Wl[KS * 64];     // 16 KB
  const int t = threadIdx.x;
  const int lane = t & 63;
  const int w = t >> 6;
  const int n0 = blockIdx.x * 64;

  float acc[16];
#pragma unroll
  for (int j = 0; j < 16; ++j) acc[j] = 0.f;

  for (int h = 0; h < K / KS; ++h) {
#pragma unroll
    for (int i = 0; i < KS * 16 / 256; ++i) {
      int li = i * 256 + t;
      float4 v = reinterpret_cast<const float4*>(W + h * KS * 64)[li];
      *reinterpret_cast<float4*>(Wl + li * 4) = v;
    }
#pragma unroll
    for (int i = 0; i < 64 * (KS / 4) / 256; ++i) {
      int li = i * 256 + t;
      int row = li / (KS / 4), c4 = li % (KS / 4);
      int node = n0 + row;
      float4 v = make_float4(0.f, 0.f, 0.f, 0.f);
      if (node < N) v = reinterpret_cast<const float4*>(x + (size_t)node * K + h * KS)[c4];
      *reinterpret_cast<float4*>(xs + row * KP + c4 * 4) = v;
    }
    __syncthreads();

    const float* xr = xs + lane * KP;
    const float* wq = Wl + w * 16;
#pragma unroll 4
    for (int kp = 0; kp < KS / 4; ++kp) {
      float4 xv = *reinterpret_cast<const float4*>(xr + kp * 4);
#pragma unroll
      for (int q = 0; q < 4; ++q) {
        int k = kp * 4 + q;
        float xq = (q == 0) ? xv.x : (q == 1) ? xv.y : (q == 2) ? xv.z : xv.w;
        const float* wk = wq + k * 64;                 // wave-uniform address
        float4 w0 = *reinterpret_cast<const float4*>(wk);
        float4 w1 = *reinterpret_cast<const float4*>(wk + 4);
        float4 w2 = *reinterpret_cast<const float4*>(wk + 8);
        float4 w3 = *reinterpret_cast<const float4*>(wk + 12);
        acc[ 0] = fmaf(xq, w0.x, acc[ 0]);
        acc[ 1] = fmaf(xq, w0.y, acc[ 1]);
        acc[ 2] = fmaf(xq, w0.z, acc[ 2]);
        acc[ 3] = fmaf(xq, w0.w, acc[ 3]);
        acc[ 4] = fmaf(xq, w1.x, acc[ 4]);
        acc[ 5] = fmaf(xq, w1.y, acc[ 5]);
        acc[ 6] = fmaf(xq, w1.z, acc[ 6]);
        acc[ 7] = fmaf(xq, w1.w, acc[ 7]);
        acc[ 8] = fmaf(xq, w2.x, acc[ 8]);
        acc[ 9] = fmaf(xq, w2.y, acc[ 9]);
        acc[10] = fmaf(xq, w2.z, acc[10]);
        acc[11] = fmaf(xq, w2.w, acc[11]);
        acc[12] = fmaf(xq, w3.x, acc[12]);
        acc[13] = fmaf(xq, w3.y, acc[13]);
        acc[14] = fmaf(xq, w3.z, acc[14]);
        acc[15] = fmaf(xq, w3.w, acc[15]);
      }
    }
    __syncthreads();   // before next half restages
  }

  int node = n0 + lane;
  if (node < N) {
    float dv = dinv[node];
    unsigned pk[8];
#pragma unroll
    for (int j = 0; j < 8; ++j) {
      unsigned lo = f2bf(acc[2 * j] * dv);
      unsigned hi = f2bf(acc[2 * j + 1] * dv);
      pk[j] = lo | (hi << 16);
    }
    unsigned* op = reinterpret_cast<unsigned*>(out + (size_t)node * 64 + w * 16);
    *reinterpret_cast<uint4*>(op)     = make_uint4(pk[0], pk[1], pk[2], pk[3]);
    *reinterpret_cast<uint4*>(op + 4) = make_uint4(pk[4], pk[5], pk[6], pk[7]);
  }
}

// Per-node slot/pos aggregation core: on return, a[j] (all lanes, folded)
// holds the raw aggregated sum (self + neighbors) for channel pos*8+j.
static __device__ __forceinline__ void gather_row(const uint4* __restrict__ hsq,
                                                  const int* __restrict__ csr,
                                                  int i, int s0, int s1,
                                                  int slot, int pos, float a[8]) {
  {
    uint4 sv = hsq[(((unsigned)i) << 3) + pos];
    if (slot == 0) {
      a[0] = bfLo(sv.x); a[1] = bfHi(sv.x); a[2] = bfLo(sv.y); a[3] = bfHi(sv.y);
      a[4] = bfLo(sv.z); a[5] = bfHi(sv.z); a[6] = bfLo(sv.w); a[7] = bfHi(sv.w);
    } else {
#pragma unroll
      for (int k = 0; k < 8; ++k) a[k] = 0.f;
    }
  }
  int j = s0;
  for (; j + 32 <= s1; j += 32) {
    int idx[4];
#pragma unroll
    for (int q = 0; q < 4; ++q) idx[q] = csr[j + 8 * q + slot];
    uint4 v[4];
#pragma unroll
    for (int q = 0; q < 4; ++q)
      v[q] = hsq[(((unsigned)idx[q]) << 3) + pos];
#pragma unroll
    for (int q = 0; q < 4; ++q) {
      a[0] += bfLo(v[q].x); a[1] += bfHi(v[q].x);
      a[2] += bfLo(v[q].y); a[3] += bfHi(v[q].y);
      a[4] += bfLo(v[q].z); a[5] += bfHi(v[q].z);
      a[6] += bfLo(v[q].w); a[7] += bfHi(v[q].w);
    }
  }
  if (j < s1) {
    int idx[4];
    bool ok[4];
#pragma unroll
    for (int q = 0; q < 4; ++q) {
      int e = j + 8 * q + slot;
      ok[q] = e < s1;
      idx[q] = csr[min(e, s1 - 1)];
    }
    uint4 v[4];
#pragma unroll
    for (int q = 0; q < 4; ++q)
      v[q] = hsq[(((unsigned)idx[q]) << 3) + pos];
#pragma unroll
    for (int q = 0; q < 4; ++q) {
      if (ok[q]) {
        a[0] += bfLo(v[q].x); a[1] += bfHi(v[q].x);
        a[2] += bfLo(v[q].y); a[3] += bfHi(v[q].y);
        a[4] += bfLo(v[q].z); a[5] += bfHi(v[q].z);
        a[6] += bfLo(v[q].w); a[7] += bfHi(v[q].w);
      }
    }
  }
#pragma unroll
  for (int k = 0; k < 8; ++k) {
    a[k] += __shfl_xor(a[k], 8);
    a[k] += __shfl_xor(a[k], 16);
    a[k] += __shfl_xor(a[k], 32);
  }
}

// Layer-1 gather fused with the 64x64 W2 transform:
// out2[i][c'] = bf16( dinv[i] * sum_k relu(dinv[i]*agg[i][k] + b1[k]) * W2[k][c'] )
// W2 staged in LDS lane-private: w2l[lane*65 + m*8 + j] = W2[pos*8+m][slot*8+j].
__global__ __launch_bounds__(256) void k_gather_w2(const unsigned short* __restrict__ hs,
                                                   const int* __restrict__ row_off,
                                                   const int* __restrict__ csr,
                                                   const float* __restrict__ dinv,
                                                   const float* __restrict__ b1,
                                                   const float* __restrict__ W2,
                                                   unsigned short* __restrict__ out2,
                                                   int N) {
  __shared__ float w2l[64 * 65];    // 16.6 KB
  const int t = threadIdx.x;
  const int lane = t & 63;
  const int slot = lane >> 3;
  const int pos  = lane & 7;
  if (t < 64) {                     // wave 0 stages W2
#pragma unroll
    for (int m = 0; m < 8; ++m) {
      const float* gp = W2 + (pos * 8 + m) * 64 + slot * 8;
      float4 wA = *reinterpret_cast<const float4*>(gp);
      float4 wB = *reinterpret_cast<const float4*>(gp + 4);
      float* dp = w2l + lane * 65 + m * 8;
      *reinterpret_cast<float4*>(dp) = wA;
      *reinterpret_cast<float4*>(dp + 4) = wB;
    }
  }
  __syncthreads();

  int wid = blockIdx.x * 4 + (t >> 6);
  int stride = gridDim.x * 4;
  const uint4* hsq = reinterpret_cast<const uint4*>(hs);
  float4 bA = reinterpret_cast<const float4*>(b1)[pos * 2];
  float4 bB = reinterpret_cast<const float4*>(b1)[pos * 2 + 1];
  const float* wl = w2l + lane * 65;

  for (int i = wid; i < N; i += stride) {
    float a[8];
    gather_row(hsq, csr, i, row_off[i], row_off[i + 1], slot, pos, a);
    float dv = dinv[i];
    float h1[8];
    h1[0] = fmaxf(fmaf(a[0], dv, bA.x), 0.f);
    h1[1] = fmaxf(fmaf(a[1], dv, bA.y), 0.f);
    h1[2] = fmaxf(fmaf(a[2], dv, bA.z), 0.f);
    h1[3] = fmaxf(fmaf(a[3], dv, bA.w), 0.f);
    h1[4] = fmaxf(fmaf(a[4], dv, bB.x), 0.f);
    h1[5] = fmaxf(fmaf(a[5], dv, bB.y), 0.f);
    h1[6] = fmaxf(fmaf(a[6], dv, bB.z), 0.f);
    h1[7] = fmaxf(fmaf(a[7], dv, bB.w), 0.f);
    // p[j] = sum_m h1[m] * W2[pos*8+m][slot*8+j]
    float p[8];
#pragma unroll
    for (int j = 0; j < 8; ++j) p[j] = 0.f;
#pragma unroll
    for (int m = 0; m < 8; ++m) {
      float4 wA = *reinterpret_cast<const float4*>(wl + m * 8);
      float4 wB = *reinterpret_cast<const float4*>(wl + m * 8 + 4);
      p[0] = fmaf(h1[m], wA.x, p[0]);
      p[1] = fmaf(h1[m], wA.y, p[1]);
      p[2] = fmaf(h1[m], wA.z, p[2]);
      p[3] = fmaf(h1[m], wA.w, p[3]);
      p[4] = fmaf(h1[m], wB.x, p[4]);
      p[5] = fmaf(h1[m], wB.y, p[5]);
      p[6] = fmaf(h1[m], wB.z, p[6]);
      p[7] = fmaf(h1[m], wB.w, p[7]);
    }
    // fold over pos (k-ranges) -> full sum over k, per channel slot*8+j
#pragma unroll
    for (int j = 0; j < 8; ++j) {
      p[j] += __shfl_xor(p[j], 1);
      p[j] += __shfl_xor(p[j], 2);
      p[j] += __shfl_xor(p[j], 4);
    }
    if (pos == 0) {                 // 8 lanes (slot 0..7) write 128B row
      unsigned pk[4];
#pragma unroll
      for (int q = 0; q < 4; ++q) {
        unsigned lo = f2bf(p[2 * q] * dv);
        unsigned hi = f2bf(p[2 * q + 1] * dv);
        pk[q] = lo | (hi << 16);
      }
      *reinterpret_cast<uint4*>(out2 + (((size_t)i) << 6) + slot * 8) =
          make_uint4(pk[0], pk[1], pk[2], pk[3]);
    }
  }
}

// Layer-2 gather fused with mean-pool accumulation:
// h2 = relu(dinv*agg + b2); gsum[batch[i]] += h2 (register-accumulated per
// wave over contiguous nodes, flushed per segment change via atomics).
__global__ __launch_bounds__(256) void k_gather_pool(const unsigned short* __restrict__ hs,
                                                     const int* __restrict__ row_off,
                                                     const int* __restrict__ csr,
                                                     const float* __restrict__ dinv,
                                                     const float* __restrict__ b2,
                                                     const int* __restrict__ batch,
                                                     float* __restrict__ gsum, int N) {
  const int t = threadIdx.x;
  const int lane = t & 63;
  const int slot = lane >> 3;
  const int pos  = lane & 7;
  const int NPW = 4;                 // nodes per wave, contiguous
  int base = (blockIdx.x * 4 + (t >> 6)) * NPW;
  if (base >= N) return;
  int end = min(base + NPW, N);
  const uint4* hsq = reinterpret_cast<const uint4*>(hs);
  float4 bA = reinterpret_cast<const float4*>(b2)[pos * 2];
  float4 bB = reinterpret_cast<const float4*>(b2)[pos * 2 + 1];

  float gacc[8];
#pragma unroll
  for (int j = 0; j < 8; ++j) gacc[j] = 0.f;
  int gprev = batch[base];

  for (int i = base; i < end; ++i) {
    float a[8];
    gather_row(hsq, csr, i, row_off[i], row_off[i + 1], slot, pos, a);
    float dv = dinv[i];
    int g = batch[i];                // wave-uniform
    if (g != gprev) {
      if (slot == 0) {
#pragma unroll
        for (int j = 0; j < 8; ++j)
          atomicAdd(&gsum[gprev * 64 + pos * 8 + j], gacc[j]);
      }
#pragma unroll
      for (int j = 0; j < 8; ++j) gacc[j] = 0.f;
      gprev = g;
    }
    gacc[0] += fmaxf(fmaf(a[0], dv, bA.x), 0.f);
    gacc[1] += fmaxf(fmaf(a[1], dv, bA.y), 0.f);
    gacc[2] += fmaxf(fmaf(a[2], dv, bA.z), 0.f);
    gacc[3] += fmaxf(fmaf(a[3], dv, bA.w), 0.f);
    gacc[4] += fmaxf(fmaf(a[4], dv, bB.x), 0.f);
    gacc[5] += fmaxf(fmaf(a[5], dv, bB.y), 0.f);
    gacc[6] += fmaxf(fmaf(a[6], dv, bB.z), 0.f);
    gacc[7] += fmaxf(fmaf(a[7], dv, bB.w), 0.f);
  }
  if (slot == 0) {
#pragma unroll
    for (int j = 0; j < 8; ++j)
      atomicAdd(&gsum[gprev * 64 + pos * 8 + j], gacc[j]);
  }
}

// Final projection; per-block binary searches for segment sizes.
__global__ void k_final(const float* __restrict__ gsum, const int* __restrict__ batch,
                        const float* __restrict__ Wp, const float* __restrict__ bp,
                        float* __restrict__ out, int N) {
  __shared__ int lb[5];
  int t = threadIdx.x;
  int g0 = blockIdx.x * 4;
  if (t < 5) lb[t] = lowerb(batch, N, g0 + t);
  __syncthreads();
  int idx = blockIdx.x * 256 + t;
  int g = idx >> 6, o = idx & 63, gl = g & 3;
  float cinv = 1.0f / fmaxf((float)(lb[gl + 1] - lb[gl]), 1.0f);
  float acc = 0.f;
#pragma unroll
  for (int k = 0; k < 64; ++k) acc += gsum[g * 64 + k] * Wp[k * 64 + o];
  out[idx] = fmaf(acc, cinv, bp[o]);
}

extern "C" void kernel_launch(void* const* d_in, const int* in_sizes, int n_in,
                              void* d_out, int out_size, void* d_ws, size_t ws_size,
                              hipStream_t stream) {
  const float* x    = (const float*)d_in[0];
  const float* W1   = (const float*)d_in[1];
  const float* b1   = (const float*)d_in[2];
  const float* W2   = (const float*)d_in[3];
  const float* b2   = (const float*)d_in[4];
  const float* Wp   = (const float*)d_in[5];
  const float* bp   = (const float*)d_in[6];
  const int*   ei   = (const int*)d_in[7];
  const int*   batch= (const int*)d_in[8];
  float* out = (float*)d_out;

  const int N = N_NODES, E = N_EDGESC;
  const int* src  = ei;        // edge_index[0]
  const int* dstp = ei + E;    // edge_index[1]

  char* wsb = (char*)d_ws;
  size_t o = 0;
  auto alloc = [&](size_t bytes) -> void* {
    void* p = wsb + o;
    o = (o + bytes + 255) & ~(size_t)255;
    return p;
  };
  int*      bcnt   = (int*)alloc((size_t)NBUCK * NBLK * 4);
  int*      btot   = (int*)alloc(NBUCK * 4);
  unsigned* bbuf   = (unsigned*)alloc((size_t)E * 4);
  int*      row_off= (int*)alloc((size_t)(N + 1) * 4);
  int*      csr    = (int*)alloc((size_t)E * 4);
  float*    dinv   = (float*)alloc((size_t)N * 4);
  unsigned short* bufA = (unsigned short*)alloc((size_t)N * 64 * 2);
  unsigned short* bufB = (unsigned short*)alloc((size_t)N * 64 * 2);
  float*    gsum   = (float*)alloc(64 * 64 * 4);

  int gN64 = (N + 63) / 64;           // 782
  int gPool = (N + 15) / 16;          // 3125 (4 waves x 4 nodes per block)

  k_hist<<<NBLK, 256, 0, stream>>>(dstp, bcnt, gsum, E);
  k_cscan<<<NBUCK, 256, 0, stream>>>(bcnt, btot);
  k_scatter<<<NBLK, 256, 0, stream>>>(src, dstp, bcnt, btot, bbuf, E);
  k_bsort<<<NBUCK, 512, 0, stream>>>(bbuf, btot, csr, row_off, dinv);

  k_gemm<128><<<gN64, 256, 0, stream>>>(x, W1, dinv, bufA, N);
  k_gather_w2<<<2048, 256, 0, stream>>>(bufA, row_off, csr, dinv, b1, W2, bufB, N);
  k_gather_pool<<<gPool, 256, 0, stream>>>(bufB, row_off, csr, dinv, b2, batch, gsum, N);
  k_final<<<16, 256, 0, stream>>>(gsum, batch, Wp, bp, out, N);
}

// Round 12
// 165.207 us; speedup vs baseline: 1.6034x; 1.6034x over previous
//
#include <hip/hip_runtime.h>

#define N_NODES  50000
#define N_EDGESC 1600000
#define N_GRAPHS 64
#define NBUCK    196      // ceil(50000/256) buckets of 256 dst nodes
#define CHUNK    2048     // edges per hist/scatter block
#define NBLK     782      // ceil(E/CHUNK)
#define NREP     32       // gsum replicas (contention spreading)

static __device__ __forceinline__ unsigned short f2bf(float f) {
  unsigned u = __float_as_uint(f);
  u += 0x7FFF + ((u >> 16) & 1);          // RNE
  return (unsigned short)(u >> 16);
}
static __device__ __forceinline__ float bfLo(unsigned u) {
  return __uint_as_float(u << 16);
}
static __device__ __forceinline__ float bfHi(unsigned u) {
  return __uint_as_float(u & 0xFFFF0000u);
}

static __device__ __forceinline__ int lowerb(const int* a, int n, int v) {
  int lo = 0, hi = n;
  while (lo < hi) { int m = (lo + hi) >> 1; if (a[m] < v) lo = m + 1; else hi = m; }
  return lo;
}

// Pass 1: per-block bucket histogram (LDS only) -> bcnt[bucket][blk].
// Also zeros the replicated gsum (spread across all blocks).
__global__ __launch_bounds__(256) void k_hist(const int* __restrict__ dst,
                                              int* __restrict__ bcnt,
                                              float* __restrict__ gsum, int E) {
  __shared__ int hist[NBUCK];
  int t = threadIdx.x, blk = blockIdx.x;
  if (t < NBUCK) hist[t] = 0;
  for (int i = blk * 256 + t; i < NREP * N_GRAPHS * 64; i += NBLK * 256)
    gsum[i] = 0.f;
  __syncthreads();
  int e0 = blk * CHUNK;
#pragma unroll
  for (int i = 0; i < CHUNK; i += 256) {
    int e = e0 + i + t;
    if (e < E) atomicAdd(&hist[dst[e] >> 8], 1);
  }
  __syncthreads();
  if (t < NBUCK) bcnt[(size_t)t * NBLK + blk] = hist[t];
}

// Pass 2: per-bucket exclusive scan across blocks (in place) + bucket totals.
__global__ __launch_bounds__(256) void k_cscan(int* __restrict__ bcnt,
                                               int* __restrict__ btot) {
  __shared__ int sm[256];
  int b = blockIdx.x, t = threadIdx.x;
  int* p = bcnt + (size_t)b * NBLK;
  int carry = 0;
  for (int tile = 0; tile < (NBLK + 255) / 256; ++tile) {
    int idx = tile * 256 + t;
    int v = (idx < NBLK) ? p[idx] : 0;
    sm[t] = v;
    __syncthreads();
    for (int o = 1; o < 256; o <<= 1) {
      int add = (t >= o) ? sm[t - o] : 0;
      __syncthreads();
      sm[t] += add;
      __syncthreads();
    }
    int incl = sm[t];
    int total = sm[255];
    if (idx < NBLK) p[idx] = incl - v + carry;
    carry += total;
    __syncthreads();
  }
  if (t == 0) btot[b] = carry;
}

// Pass 3: scatter edges to final bucket-contiguous positions.
__global__ __launch_bounds__(256) void k_scatter(const int* __restrict__ src,
                                                 const int* __restrict__ dst,
                                                 const int* __restrict__ bcnt,
                                                 const int* __restrict__ btot,
                                                 unsigned* __restrict__ bbuf, int E) {
  __shared__ int base[NBUCK], cur[NBUCK], sm[256];
  int t = threadIdx.x, blk = blockIdx.x;
  int v = (t < NBUCK) ? btot[t] : 0;
  sm[t] = v;
  __syncthreads();
  for (int o = 1; o < 256; o <<= 1) {
    int add = (t >= o) ? sm[t - o] : 0;
    __syncthreads();
    sm[t] += add;
    __syncthreads();
  }
  if (t < NBUCK) {
    base[t] = (sm[t] - v) + bcnt[(size_t)t * NBLK + blk];
    cur[t] = 0;
  }
  __syncthreads();
  int e0 = blk * CHUNK;
#pragma unroll
  for (int i = 0; i < CHUNK; i += 256) {
    int e = e0 + i + t;
    if (e < E) {
      int d = dst[e], b = d >> 8;
      int pos = base[b] + atomicAdd(&cur[b], 1);
      bbuf[pos] = ((unsigned)(d & 255) << 24) | (unsigned)src[e];
    }
  }
}

// Pass 4: per-bucket counting sort -> csr + row_off + dinv. 512 threads.
__global__ __launch_bounds__(512) void k_bsort(const unsigned* __restrict__ bbuf,
                                               const int* __restrict__ btot,
                                               int* __restrict__ csr,
                                               int* __restrict__ row_off,
                                               float* __restrict__ dinv) {
  __shared__ int hist[256], off[256], cur[256], sm[256];
  int b = blockIdx.x, t = threadIdx.x;
  if (t < 256) {
    int v = (t < NBUCK) ? btot[t] : 0;
    sm[t] = v;
    hist[t] = 0; cur[t] = 0;
  }
  __syncthreads();
  for (int o = 1; o < 256; o <<= 1) {
    int add = 0;
    if (t < 256 && t >= o) add = sm[t - o];
    __syncthreads();
    if (t < 256) sm[t] += add;
    __syncthreads();
  }
  int gb = (b > 0) ? sm[b - 1] : 0;
  int cnt = btot[b];
  const unsigned* bp = bbuf + gb;
  for (int i = t; i < cnt; i += 512) atomicAdd(&hist[bp[i] >> 24], 1);
  __syncthreads();
  if (t < 256) off[t] = hist[t];
  __syncthreads();
  for (int o = 1; o < 256; o <<= 1) {
    int add = 0;
    if (t < 256 && t >= o) add = off[t - o];
    __syncthreads();
    if (t < 256) off[t] += add;
    __syncthreads();
  }
  if (t < 256) {
    int excl = off[t] - hist[t];
    off[t] = excl;
    int idx = (b << 8) + t;
    if (idx <= N_NODES) row_off[idx] = gb + excl;
    if (idx < N_NODES)  dinv[idx] = rsqrtf((float)(hist[t] + 1));  // +1 self-loop
  }
  __syncthreads();
  for (int i = t; i < cnt; i += 512) {
    unsigned v = bp[i];
    int ld = v >> 24;
    int pos = atomicAdd(&cur[ld], 1);
    csr[gb + off[ld] + pos] = (int)(v & 0xFFFFFFu);
  }
}

// out_bf16[i][c] = bf16( (x[i,:] @ W[:,c]) * dinv[i] )
template <int K>
__global__ __launch_bounds__(256) void k_gemm(const float* __restrict__ x,
                                              const float* __restrict__ W,
                                              const float* __restrict__ dinv,
                                              unsigned short* __restrict__ out, int N) {
  constexpr int KS = 64;            // K-step
  constexpr int KP = KS + 4;        // padded xs row stride
  __shared__ float xs[64 * KP];     // 17.4 KB
  __shared__ float Wl[KS * 64];     // 16 KB
  const int t = threadIdx.x;
  const int lane = t & 63;
  const int w = t >> 6;
  const int n0 = blockIdx.x * 64;

  float acc[16];
#pragma unroll
  for (int j = 0; j < 16; ++j) acc[j] = 0.f;

  for (int h = 0; h < K / KS; ++h) {
#pragma unroll
    for (int i = 0; i < KS * 16 / 256; ++i) {
      int li = i * 256 + t;
      float4 v = reinterpret_cast<const float4*>(W + h * KS * 64)[li];
      *reinterpret_cast<float4*>(Wl + li * 4) = v;
    }
#pragma unroll
    for (int i = 0; i < 64 * (KS / 4) / 256; ++i) {
      int li = i * 256 + t;
      int row = li / (KS / 4), c4 = li % (KS / 4);
      int node = n0 + row;
      float4 v = make_float4(0.f, 0.f, 0.f, 0.f);
      if (node < N) v = reinterpret_cast<const float4*>(x + (size_t)node * K + h * KS)[c4];
      *reinterpret_cast<float4*>(xs + row * KP + c4 * 4) = v;
    }
    __syncthreads();

    const float* xr = xs + lane * KP;
    const float* wq = Wl + w * 16;
#pragma unroll 4
    for (int kp = 0; kp < KS / 4; ++kp) {
      float4 xv = *reinterpret_cast<const float4*>(xr + kp * 4);
#pragma unroll
      for (int q = 0; q < 4; ++q) {
        int k = kp * 4 + q;
        float xq = (q == 0) ? xv.x : (q == 1) ? xv.y : (q == 2) ? xv.z : xv.w;
        const float* wk = wq + k * 64;                 // wave-uniform address
        float4 w0 = *reinterpret_cast<const float4*>(wk);
        float4 w1 = *reinterpret_cast<const float4*>(wk + 4);
        float4 w2 = *reinterpret_cast<const float4*>(wk + 8);
        float4 w3 = *reinterpret_cast<const float4*>(wk + 12);
        acc[ 0] = fmaf(xq, w0.x, acc[ 0]);
        acc[ 1] = fmaf(xq, w0.y, acc[ 1]);
        acc[ 2] = fmaf(xq, w0.z, acc[ 2]);
        acc[ 3] = fmaf(xq, w0.w, acc[ 3]);
        acc[ 4] = fmaf(xq, w1.x, acc[ 4]);
        acc[ 5] = fmaf(xq, w1.y, acc[ 5]);
        acc[ 6] = fmaf(xq, w1.z, acc[ 6]);
        acc[ 7] = fmaf(xq, w1.w, acc[ 7]);
        acc[ 8] = fmaf(xq, w2.x, acc[ 8]);
        acc[ 9] = fmaf(xq, w2.y, acc[ 9]);
        acc[10] = fmaf(xq, w2.z, acc[10]);
        acc[11] = fmaf(xq, w2.w, acc[11]);
        acc[12] = fmaf(xq, w3.x, acc[12]);
        acc[13] = fmaf(xq, w3.y, acc[13]);
        acc[14] = fmaf(xq, w3.z, acc[14]);
        acc[15] = fmaf(xq, w3.w, acc[15]);
      }
    }
    __syncthreads();   // before next half restages
  }

  int node = n0 + lane;
  if (node < N) {
    float dv = dinv[node];
    unsigned pk[8];
#pragma unroll
    for (int j = 0; j < 8; ++j) {
      unsigned lo = f2bf(acc[2 * j] * dv);
      unsigned hi = f2bf(acc[2 * j + 1] * dv);
      pk[j] = lo | (hi << 16);
    }
    unsigned* op = reinterpret_cast<unsigned*>(out + (size_t)node * 64 + w * 16);
    *reinterpret_cast<uint4*>(op)     = make_uint4(pk[0], pk[1], pk[2], pk[3]);
    *reinterpret_cast<uint4*>(op + 4) = make_uint4(pk[4], pk[5], pk[6], pk[7]);
  }
}

// Per-node slot/pos aggregation core: on return, a[j] (all lanes, folded)
// holds the raw aggregated sum (self + neighbors) for channel pos*8+j.
static __device__ __forceinline__ void gather_row(const uint4* __restrict__ hsq,
                                                  const int* __restrict__ csr,
                                                  int i, int s0, int s1,
                                                  int slot, int pos, float a[8]) {
  {
    uint4 sv = hsq[(((unsigned)i) << 3) + pos];
    if (slot == 0) {
      a[0] = bfLo(sv.x); a[1] = bfHi(sv.x); a[2] = bfLo(sv.y); a[3] = bfHi(sv.y);
      a[4] = bfLo(sv.z); a[5] = bfHi(sv.z); a[6] = bfLo(sv.w); a[7] = bfHi(sv.w);
    } else {
#pragma unroll
      for (int k = 0; k < 8; ++k) a[k] = 0.f;
    }
  }
  int j = s0;
  for (; j + 32 <= s1; j += 32) {
    int idx[4];
#pragma unroll
    for (int q = 0; q < 4; ++q) idx[q] = csr[j + 8 * q + slot];
    uint4 v[4];
#pragma unroll
    for (int q = 0; q < 4; ++q)
      v[q] = hsq[(((unsigned)idx[q]) << 3) + pos];
#pragma unroll
    for (int q = 0; q < 4; ++q) {
      a[0] += bfLo(v[q].x); a[1] += bfHi(v[q].x);
      a[2] += bfLo(v[q].y); a[3] += bfHi(v[q].y);
      a[4] += bfLo(v[q].z); a[5] += bfHi(v[q].z);
      a[6] += bfLo(v[q].w); a[7] += bfHi(v[q].w);
    }
  }
  if (j < s1) {
    int idx[4];
    bool ok[4];
#pragma unroll
    for (int q = 0; q < 4; ++q) {
      int e = j + 8 * q + slot;
      ok[q] = e < s1;
      idx[q] = csr[min(e, s1 - 1)];
    }
    uint4 v[4];
#pragma unroll
    for (int q = 0; q < 4; ++q)
      v[q] = hsq[(((unsigned)idx[q]) << 3) + pos];
#pragma unroll
    for (int q = 0; q < 4; ++q) {
      if (ok[q]) {
        a[0] += bfLo(v[q].x); a[1] += bfHi(v[q].x);
        a[2] += bfLo(v[q].y); a[3] += bfHi(v[q].y);
        a[4] += bfLo(v[q].z); a[5] += bfHi(v[q].z);
        a[6] += bfLo(v[q].w); a[7] += bfHi(v[q].w);
      }
    }
  }
#pragma unroll
  for (int k = 0; k < 8; ++k) {
    a[k] += __shfl_xor(a[k], 8);
    a[k] += __shfl_xor(a[k], 16);
    a[k] += __shfl_xor(a[k], 32);
  }
}

// Layer-1 gather fused with the 64x64 W2 transform.
__global__ __launch_bounds__(256) void k_gather_w2(const unsigned short* __restrict__ hs,
                                                   const int* __restrict__ row_off,
                                                   const int* __restrict__ csr,
                                                   const float* __restrict__ dinv,
                                                   const float* __restrict__ b1,
                                                   const float* __restrict__ W2,
                                                   unsigned short* __restrict__ out2,
                                                   int N) {
  __shared__ float w2l[64 * 65];    // 16.6 KB
  const int t = threadIdx.x;
  const int lane = t & 63;
  const int slot = lane >> 3;
  const int pos  = lane & 7;
  if (t < 64) {                     // wave 0 stages W2
#pragma unroll
    for (int m = 0; m < 8; ++m) {
      const float* gp = W2 + (pos * 8 + m) * 64 + slot * 8;
      float4 wA = *reinterpret_cast<const float4*>(gp);
      float4 wB = *reinterpret_cast<const float4*>(gp + 4);
      float* dp = w2l + lane * 65 + m * 8;
      *reinterpret_cast<float4*>(dp) = wA;
      *reinterpret_cast<float4*>(dp + 4) = wB;
    }
  }
  __syncthreads();

  int wid = blockIdx.x * 4 + (t >> 6);
  int stride = gridDim.x * 4;
  const uint4* hsq = reinterpret_cast<const uint4*>(hs);
  float4 bA = reinterpret_cast<const float4*>(b1)[pos * 2];
  float4 bB = reinterpret_cast<const float4*>(b1)[pos * 2 + 1];
  const float* wl = w2l + lane * 65;

  for (int i = wid; i < N; i += stride) {
    float a[8];
    gather_row(hsq, csr, i, row_off[i], row_off[i + 1], slot, pos, a);
    float dv = dinv[i];
    float h1[8];
    h1[0] = fmaxf(fmaf(a[0], dv, bA.x), 0.f);
    h1[1] = fmaxf(fmaf(a[1], dv, bA.y), 0.f);
    h1[2] = fmaxf(fmaf(a[2], dv, bA.z), 0.f);
    h1[3] = fmaxf(fmaf(a[3], dv, bA.w), 0.f);
    h1[4] = fmaxf(fmaf(a[4], dv, bB.x), 0.f);
    h1[5] = fmaxf(fmaf(a[5], dv, bB.y), 0.f);
    h1[6] = fmaxf(fmaf(a[6], dv, bB.z), 0.f);
    h1[7] = fmaxf(fmaf(a[7], dv, bB.w), 0.f);
    float p[8];
#pragma unroll
    for (int j = 0; j < 8; ++j) p[j] = 0.f;
#pragma unroll
    for (int m = 0; m < 8; ++m) {
      float4 wA = *reinterpret_cast<const float4*>(wl + m * 8);
      float4 wB = *reinterpret_cast<const float4*>(wl + m * 8 + 4);
      p[0] = fmaf(h1[m], wA.x, p[0]);
      p[1] = fmaf(h1[m], wA.y, p[1]);
      p[2] = fmaf(h1[m], wA.z, p[2]);
      p[3] = fmaf(h1[m], wA.w, p[3]);
      p[4] = fmaf(h1[m], wB.x, p[4]);
      p[5] = fmaf(h1[m], wB.y, p[5]);
      p[6] = fmaf(h1[m], wB.z, p[6]);
      p[7] = fmaf(h1[m], wB.w, p[7]);
    }
#pragma unroll
    for (int j = 0; j < 8; ++j) {
      p[j] += __shfl_xor(p[j], 1);
      p[j] += __shfl_xor(p[j], 2);
      p[j] += __shfl_xor(p[j], 4);
    }
    if (pos == 0) {                 // 8 lanes (slot 0..7) write 128B row
      unsigned pk[4];
#pragma unroll
      for (int q = 0; q < 4; ++q) {
        unsigned lo = f2bf(p[2 * q] * dv);
        unsigned hi = f2bf(p[2 * q + 1] * dv);
        pk[q] = lo | (hi << 16);
      }
      *reinterpret_cast<uint4*>(out2 + (((size_t)i) << 6) + slot * 8) =
          make_uint4(pk[0], pk[1], pk[2], pk[3]);
    }
  }
}

// Layer-2 gather fused with mean-pool accumulation (replicated gsum).
// Flush: shfl-transpose so lane l holds channel l, then ONE 64-lane atomic.
__global__ __launch_bounds__(256) void k_gather_pool(const unsigned short* __restrict__ hs,
                                                     const int* __restrict__ row_off,
                                                     const int* __restrict__ csr,
                                                     const float* __restrict__ dinv,
                                                     const float* __restrict__ b2,
                                                     const int* __restrict__ batch,
                                                     float* __restrict__ gsum, int N) {
  const int t = threadIdx.x;
  const int lane = t & 63;
  const int slot = lane >> 3;
  const int pos  = lane & 7;
  const int NPW = 8;                 // nodes per wave, contiguous
  int wid = blockIdx.x * 4 + (t >> 6);
  int base = wid * NPW;
  if (base >= N) return;
  int end = min(base + NPW, N);
  int rep = wid & (NREP - 1);
  const uint4* hsq = reinterpret_cast<const uint4*>(hs);
  float4 bA = reinterpret_cast<const float4*>(b2)[pos * 2];
  float4 bB = reinterpret_cast<const float4*>(b2)[pos * 2 + 1];
  const int srcl = ((lane & 7) << 3) | (lane >> 3);

  float gacc[8];
#pragma unroll
  for (int j = 0; j < 8; ++j) gacc[j] = 0.f;
  int gprev = batch[base];

  for (int i = base; i < end; ++i) {
    float a[8];
    gather_row(hsq, csr, i, row_off[i], row_off[i + 1], slot, pos, a);
    float dv = dinv[i];
    int g = batch[i];                // wave-uniform
    if (g != gprev) {
      float v = 0.f;
#pragma unroll
      for (int j = 0; j < 8; ++j) {
        float tv = __shfl(gacc[j], srcl);
        if ((lane & 7) == j) v = tv;
      }
      atomicAdd(&gsum[(rep * N_GRAPHS + gprev) * 64 + lane], v);
#pragma unroll
      for (int j = 0; j < 8; ++j) gacc[j] = 0.f;
      gprev = g;
    }
    gacc[0] += fmaxf(fmaf(a[0], dv, bA.x), 0.f);
    gacc[1] += fmaxf(fmaf(a[1], dv, bA.y), 0.f);
    gacc[2] += fmaxf(fmaf(a[2], dv, bA.z), 0.f);
    gacc[3] += fmaxf(fmaf(a[3], dv, bA.w), 0.f);
    gacc[4] += fmaxf(fmaf(a[4], dv, bB.x), 0.f);
    gacc[5] += fmaxf(fmaf(a[5], dv, bB.y), 0.f);
    gacc[6] += fmaxf(fmaf(a[6], dv, bB.z), 0.f);
    gacc[7] += fmaxf(fmaf(a[7], dv, bB.w), 0.f);
  }
  {
    float v = 0.f;
#pragma unroll
    for (int j = 0; j < 8; ++j) {
      float tv = __shfl(gacc[j], srcl);
      if ((lane & 7) == j) v = tv;
    }
    atomicAdd(&gsum[(rep * N_GRAPHS + gprev) * 64 + lane], v);
  }
}

// Final projection; reduce the NREP gsum replicas in LDS first.
__global__ void k_final(const float* __restrict__ gsum, const int* __restrict__ batch,
                        const float* __restrict__ Wp, const float* __restrict__ bp,
                        float* __restrict__ out, int N) {
  __shared__ int lb[5];
  __shared__ float gs[4][64];
  int t = threadIdx.x;
  int g0 = blockIdx.x * 4;
  if (t < 5) lb[t] = lowerb(batch, N, g0 + t);
  {
    int gl = t >> 6, k = t & 63;
    float s = 0.f;
#pragma unroll
    for (int r = 0; r < NREP; ++r)
      s += gsum[(r * N_GRAPHS + g0 + gl) * 64 + k];
    gs[gl][k] = s;
  }
  __syncthreads();
  int idx = blockIdx.x * 256 + t;
  int o = idx & 63, gl = (idx >> 6) & 3;
  float cinv = 1.0f / fmaxf((float)(lb[gl + 1] - lb[gl]), 1.0f);
  float acc = 0.f;
#pragma unroll
  for (int k = 0; k < 64; ++k) acc += gs[gl][k] * Wp[k * 64 + o];
  out[idx] = fmaf(acc, cinv, bp[o]);
}

extern "C" void kernel_launch(void* const* d_in, const int* in_sizes, int n_in,
                              void* d_out, int out_size, void* d_ws, size_t ws_size,
                              hipStream_t stream) {
  const float* x    = (const float*)d_in[0];
  const float* W1   = (const float*)d_in[1];
  const float* b1   = (const float*)d_in[2];
  const float* W2   = (const float*)d_in[3];
  const float* b2   = (const float*)d_in[4];
  const float* Wp   = (const float*)d_in[5];
  const float* bp   = (const float*)d_in[6];
  const int*   ei   = (const int*)d_in[7];
  const int*   batch= (const int*)d_in[8];
  float* out = (float*)d_out;

  const int N = N_NODES, E = N_EDGESC;
  const int* src  = ei;        // edge_index[0]
  const int* dstp = ei + E;    // edge_index[1]

  char* wsb = (char*)d_ws;
  size_t o = 0;
  auto alloc = [&](size_t bytes) -> void* {
    void* p = wsb + o;
    o = (o + bytes + 255) & ~(size_t)255;
    return p;
  };
  int*      bcnt   = (int*)alloc((size_t)NBUCK * NBLK * 4);
  int*      btot   = (int*)alloc(NBUCK * 4);
  unsigned* bbuf   = (unsigned*)alloc((size_t)E * 4);
  int*      row_off= (int*)alloc((size_t)(N + 1) * 4);
  int*      csr    = (int*)alloc((size_t)E * 4);
  float*    dinv   = (float*)alloc((size_t)N * 4);
  unsigned short* bufA = (unsigned short*)alloc((size_t)N * 64 * 2);
  unsigned short* bufB = (unsigned short*)alloc((size_t)N * 64 * 2);
  float*    gsum   = (float*)alloc((size_t)NREP * N_GRAPHS * 64 * 4);

  int gN64 = (N + 63) / 64;             // 782
  int gPool = (N + 31) / 32;            // 1563 (4 waves x 8 nodes per block)

  k_hist<<<NBLK, 256, 0, stream>>>(dstp, bcnt, gsum, E);
  k_cscan<<<NBUCK, 256, 0, stream>>>(bcnt, btot);
  k_scatter<<<NBLK, 256, 0, stream>>>(src, dstp, bcnt, btot, bbuf, E);
  k_bsort<<<NBUCK, 512, 0, stream>>>(bbuf, btot, csr, row_off, dinv);

  k_gemm<128><<<gN64, 256, 0, stream>>>(x, W1, dinv, bufA, N);
  k_gather_w2<<<2048, 256, 0, stream>>>(bufA, row_off, csr, dinv, b1, W2, bufB, N);
  k_gather_pool<<<gPool, 256, 0, stream>>>(bufB, row_off, csr, dinv, b2, batch, gsum, N);
  k_final<<<16, 256, 0, stream>>>(gsum, batch, Wp, bp, out, N);
}